// Round 3
// baseline (81.747 us; speedup 1.0000x reference)
//
#include <hip/hip_runtime.h>
#include <stdint.h>

#define HID 128

typedef __attribute__((ext_vector_type(8))) __bf16 bf16x8;
typedef __attribute__((ext_vector_type(4))) float floatx4;

// load 8 consecutive fp32 and convert to a bf16x8 fragment.
// Native __bf16 casts compile to v_cvt_pk_bf16_f32 (RNE) on gfx950.
__device__ inline bf16x8 load_cvt8(const float* __restrict__ p) {
    floatx4 v0 = *(const floatx4*)(p);
    floatx4 v1 = *(const floatx4*)(p + 4);
    bf16x8 r;
    r[0] = (__bf16)v0[0]; r[1] = (__bf16)v0[1];
    r[2] = (__bf16)v0[2]; r[3] = (__bf16)v0[3];
    r[4] = (__bf16)v1[0]; r[5] = (__bf16)v1[1];
    r[6] = (__bf16)v1[2]; r[7] = (__bf16)v1[3];
    return r;
}

// Block = 256 threads (4 waves) owns 64 rows x 32 cols (one column-quarter).
// Wave w computes rows [blk+16w, blk+16w+16) x 32 cols.
// Grid = (N/64) x 4 = 1024 blocks -> 4 blocks/CU, 16 waves/CU, 4 waves/SIMD
// (the previous version had 256 blocks = 1 wave/SIMD: stage latency and
// barriers were fully exposed -> 34.6 us at only ~16% of HBM BW).
// Per species-segment, W[z] rows [c0,c0+32) (16 KB fp32) are staged to 8 KB
// LDS bf16 with the XOR chunk-swizzle (conflict-free ds_read_b128 B-frags).
// XCD-chunked bijective swizzle puts 32 consecutive row-tiles x all 4
// column-quarters on one XCD: m_curr re-reads (4x) and cross-block W
// re-reads become L2 hits instead of HBM traffic.
__global__ __launch_bounds__(256, 4) void elem_update_kernel(
    const float* __restrict__ h_prev,
    const float* __restrict__ m_curr,
    const int* __restrict__ atom_types,
    const float* __restrict__ weight,
    float* __restrict__ out)
{
    __shared__ __attribute__((aligned(16))) unsigned short Wlds[32 * HID]; // 8 KB bf16

    const int tid  = threadIdx.x;
    const int lane = tid & 63;
    const int wave = tid >> 6;
    const int l15  = lane & 15;
    const int quad = lane >> 4;

    // XCD-chunked swizzle (bijective: gridDim.x = 1024, divisible by 8).
    // XCD k (= bid%8) executes logical wgs [k*128, (k+1)*128): row-tile-major,
    // cq fastest -> same-XCD blocks share W[z] panels and m_curr rows in L2.
    const int nwg = gridDim.x;
    const int bid = blockIdx.x;
    const int wg  = (bid & 7) * (nwg >> 3) + (bid >> 3);

    const int row_tile = wg >> 2;            // 64-row tile index
    const int cq       = wg & 3;             // column quarter
    const int blk_r0   = row_tile * 64;
    const int wr0      = blk_r0 + wave * 16; // wave's 16 rows
    const int c0       = cq * 32;

    // block's 64 species, lane-indexed (identical across the 4 waves ->
    // segment loop is block-uniform, barriers are safe)
    const int t = atom_types[blk_r0 + lane];

    // A-frags: lane's m_curr row = wr0 + l15, full K (species- and cq-independent)
    bf16x8 a[4];
    #pragma unroll
    for (int kk = 0; kk < 4; ++kk)
        a[kk] = load_cvt8(m_curr + (size_t)(wr0 + l15) * HID + kk * 32 + quad * 8);

    int s = 0;
    while (s < 64) {
        const int z = __shfl(t, s);                      // block-uniform species
        unsigned long long neq = __ballot(t != z);
        unsigned long long bits = (s < 63) ? (neq & ~((2ull << s) - 1ull)) : 0ull;
        const int e = bits ? (int)__builtin_ctzll(bits) : 64;   // segment [s,e)

        // ---- stage W[z] rows [c0, c0+32) -> LDS bf16, swizzled ----
        __syncthreads();   // previous segment's readers are done with Wlds
        const float* __restrict__ Wz = weight + (size_t)z * (HID * HID) + (size_t)c0 * HID;
        #pragma unroll
        for (int i = 0; i < 2; ++i) {
            const int linear = i * 2048 + tid * 8;       // 4096 elements total
            const int rr  = linear >> 7;                 // W row - c0, in [0,32)
            const int col = linear & 127;                // k index, multiple of 8
            bf16x8 b = load_cvt8(Wz + linear);           // coalesced float4 x2
            const int chunk = (col >> 3) ^ (rr & 15);    // XOR swizzle on 16B chunks
            *(bf16x8*)((char*)Wlds + rr * 256 + chunk * 16) = b;  // ds_write_b128
        }
        __syncthreads();

        // ---- compute: waves whose rows intersect [s,e) ----
        const int lo = (s > wave * 16) ? s : wave * 16;
        const int hi = (e < wave * 16 + 16) ? e : wave * 16 + 16;
        if (lo < hi) {
            // C-init = h_prev at D-layout positions: row = quad*4+r, col = c0+nt*16+l15
            floatx4 acc[2];
            #pragma unroll
            for (int nt = 0; nt < 2; ++nt) {
                #pragma unroll
                for (int r = 0; r < 4; ++r) {
                    acc[nt][r] = h_prev[(size_t)(wr0 + quad * 4 + r) * HID + c0 + nt * 16 + l15];
                }
            }
            #pragma unroll
            for (int kk = 0; kk < 4; ++kk) {
                #pragma unroll
                for (int nt = 0; nt < 2; ++nt) {
                    // B[k][n=l15] = W[n][k]; LDS row rr = nt*16+l15, chunk = kk*4+quad (swizzled)
                    const int chunk = (kk * 4 + quad) ^ l15;     // rr & 15 == l15
                    bf16x8 b = *(const bf16x8*)((const char*)Wlds +
                                                (nt * 16 + l15) * 256 + chunk * 16);
                    acc[nt] = __builtin_amdgcn_mfma_f32_16x16x32_bf16(a[kk], b, acc[nt], 0, 0, 0);
                }
            }
            // epilogue: store only rows inside the segment
            #pragma unroll
            for (int nt = 0; nt < 2; ++nt) {
                #pragma unroll
                for (int r = 0; r < 4; ++r) {
                    const int brow = wave * 16 + quad * 4 + r;   // block-relative row
                    if (brow >= lo && brow < hi) {
                        out[(size_t)(blk_r0 + brow) * HID + c0 + nt * 16 + l15] = acc[nt][r];
                    }
                }
            }
        }
        s = e;
    }
}

extern "C" void kernel_launch(void* const* d_in, const int* in_sizes, int n_in,
                              void* d_out, int out_size, void* d_ws, size_t ws_size,
                              hipStream_t stream) {
    const float* h_prev     = (const float*)d_in[0];
    const float* m_curr     = (const float*)d_in[1];
    const int*   atom_types = (const int*)d_in[2];
    const float* weight     = (const float*)d_in[3];
    float*       out        = (float*)d_out;

    const int n_nodes = in_sizes[2];       // 16384
    const int blocks  = (n_nodes / 64) * 4;  // 1024 blocks
    elem_update_kernel<<<blocks, 256, 0, stream>>>(h_prev, m_curr, atom_types, weight, out);
}

// Round 4
// 79.814 us; speedup vs baseline: 1.0242x; 1.0242x over previous
//
#include <hip/hip_runtime.h>
#include <stdint.h>

#define HID 128

typedef __attribute__((ext_vector_type(8))) __bf16 bf16x8;
typedef __attribute__((ext_vector_type(4))) float floatx4;

// load 8 consecutive fp32 and convert to a bf16x8 fragment.
// Native __bf16 casts compile to v_cvt_pk_bf16_f32 (RNE) on gfx950.
__device__ inline bf16x8 load_cvt8(const float* __restrict__ p) {
    floatx4 v0 = *(const floatx4*)(p);
    floatx4 v1 = *(const floatx4*)(p + 4);
    bf16x8 r;
    r[0] = (__bf16)v0[0]; r[1] = (__bf16)v0[1];
    r[2] = (__bf16)v0[2]; r[3] = (__bf16)v0[3];
    r[4] = (__bf16)v1[0]; r[5] = (__bf16)v1[1];
    r[6] = (__bf16)v1[2]; r[7] = (__bf16)v1[3];
    return r;
}

// Block = 256 threads (4 waves) owns 64 rows x 128 cols (best-measured R2
// structure: 79.1 us total). Wave w computes rows [blk+16w, blk+16w+16),
// all 128 columns. Per species-segment (block-uniform via ballot on sorted
// atom_types), W[z] (128x128 fp32) is cooperatively staged into 32 KB LDS as
// bf16 with an XOR chunk-swizzle (conflict-free stride-256B ds_read_b128).
//
// NEW vs R2: bijective XCD-chunk swizzle. Default blockIdx round-robins
// XCDs (bid%8 = XCD), so consecutive row-tiles -- which share a species run
// (avg run 138 rows ~ 2.2 tiles) -- land on different XCDs and each re-stages
// W[z] from HBM. Remapped, XCD k owns row-tiles [k*32,(k+1)*32): per-XCD
// working set ~1 MB W + 1 MB m_curr << 4 MB L2, so W re-stages become L2
// hits. Expected W HBM traffic ~24 MB -> ~8 MB.
__global__ __launch_bounds__(256, 2) void elem_update_kernel(
    const float* __restrict__ h_prev,
    const float* __restrict__ m_curr,
    const int* __restrict__ atom_types,
    const float* __restrict__ weight,
    float* __restrict__ out)
{
    __shared__ __attribute__((aligned(16))) unsigned short Wlds[HID * HID]; // bf16, 32 KB

    const int tid  = threadIdx.x;
    const int lane = tid & 63;
    const int wave = tid >> 6;
    const int l15  = lane & 15;
    const int quad = lane >> 4;

    // XCD-chunked bijective swizzle (gridDim.x = 256, divisible by 8).
    const int nwg = gridDim.x;
    const int bid = blockIdx.x;
    const int wg  = ((nwg & 7) == 0) ? ((bid & 7) * (nwg >> 3) + (bid >> 3)) : bid;

    const int blk_r0 = wg * 64;              // block's 64 rows
    const int wr0    = blk_r0 + wave * 16;   // wave's 16 rows

    // block's 64 species, lane-indexed (identical across the 4 waves ->
    // segment loop is block-uniform, barriers are safe)
    const int t = atom_types[blk_r0 + lane];

    // A-frags: lane's m_curr row = wr0 + l15, cols kk*32 + quad*8 (species-independent, hoist)
    bf16x8 a[4];
    #pragma unroll
    for (int kk = 0; kk < 4; ++kk)
        a[kk] = load_cvt8(m_curr + (size_t)(wr0 + l15) * HID + kk * 32 + quad * 8);

    int s = 0;
    while (s < 64) {
        const int z = __shfl(t, s);                      // block-uniform species
        unsigned long long neq = __ballot(t != z);
        unsigned long long bits = (s < 63) ? (neq & ~((2ull << s) - 1ull)) : 0ull;
        const int e = bits ? (int)__builtin_ctzll(bits) : 64;   // segment [s,e) in block rows

        // ---- stage W[z] -> LDS bf16, swizzled ----
        __syncthreads();   // previous segment's readers are done with Wlds
        const float* __restrict__ Wz = weight + (size_t)z * (HID * HID);
        #pragma unroll
        for (int i = 0; i < 8; ++i) {
            const int linear = i * 2048 + tid * 8;       // element index, 8 floats/thread/iter
            const int row = linear >> 7;
            const int col = linear & 127;                // multiple of 8
            bf16x8 b = load_cvt8(Wz + linear);           // coalesced float4 x2
            const int chunk = (col >> 3) ^ (row & 15);   // XOR swizzle on 16B chunks
            *(bf16x8*)((char*)Wlds + row * 256 + chunk * 16) = b;  // ds_write_b128
        }
        __syncthreads();

        // ---- compute: waves whose rows intersect [s,e) ----
        const int lo = (s > wave * 16) ? s : wave * 16;
        const int hi = (e < wave * 16 + 16) ? e : wave * 16 + 16;
        if (lo < hi) {
            // C-init = h_prev at D-layout positions: row = quad*4+r, col = nt*16+l15
            floatx4 acc[8];
            #pragma unroll
            for (int nt = 0; nt < 8; ++nt) {
                #pragma unroll
                for (int r = 0; r < 4; ++r) {
                    acc[nt][r] = h_prev[(size_t)(wr0 + quad * 4 + r) * HID + nt * 16 + l15];
                }
            }
            #pragma unroll
            for (int kk = 0; kk < 4; ++kk) {
                #pragma unroll
                for (int nt = 0; nt < 8; ++nt) {
                    // B[k][n=l15] = W[n][k]; W row = nt*16+l15, k-chunk = kk*4+quad, swizzled
                    const int chunk = (kk * 4 + quad) ^ l15;   // row&15 == l15 here
                    bf16x8 b = *(const bf16x8*)((const char*)Wlds +
                                                (nt * 16 + l15) * 256 + chunk * 16);
                    acc[nt] = __builtin_amdgcn_mfma_f32_16x16x32_bf16(a[kk], b, acc[nt], 0, 0, 0);
                }
            }
            // epilogue: store only rows inside the segment
            #pragma unroll
            for (int nt = 0; nt < 8; ++nt) {
                #pragma unroll
                for (int r = 0; r < 4; ++r) {
                    const int brow = wave * 16 + quad * 4 + r;   // block-relative row
                    if (brow >= lo && brow < hi) {
                        out[(size_t)(blk_r0 + brow) * HID + nt * 16 + l15] = acc[nt][r];
                    }
                }
            }
        }
        s = e;
    }
}

extern "C" void kernel_launch(void* const* d_in, const int* in_sizes, int n_in,
                              void* d_out, int out_size, void* d_ws, size_t ws_size,
                              hipStream_t stream) {
    const float* h_prev     = (const float*)d_in[0];
    const float* m_curr     = (const float*)d_in[1];
    const int*   atom_types = (const int*)d_in[2];
    const float* weight     = (const float*)d_in[3];
    float*       out        = (float*)d_out;

    const int n_nodes = in_sizes[2];       // 16384
    const int blocks  = n_nodes / 64;      // 256 blocks x 4 waves
    elem_update_kernel<<<blocks, 256, 0, stream>>>(h_prev, m_curr, atom_types, weight, out);
}